// Round 1
// baseline (607.935 us; speedup 1.0000x reference)
//
#include <hip/hip_runtime.h>
#include <hip/hip_cooperative_groups.h>
#include <math.h>

namespace cg = cooperative_groups;

#define NXY    192
#define CELLS  (NXY*NXY)
#define NBATCH 4
#define NSTEPS 256
#define TCH    16                 // steps per chunk (= halo radius)
#define NCHUNK (NSTEPS/TCH)       // 16
#define TPB    512                // 8 waves -> 2 waves/SIMD
#define NW     8
#define RPL    5                  // rows per wave (40-row window / 8 waves)
#define OUTR   6                  // out rows per tile
#define NBLKS  256                // 32 row-tiles x 2 col-tiles x 4 batches
// in-tile 128 cols x 40 rows; out-tile 96 cols x 6 rows (window rows [17,23))

// workspace layout (float offsets): 16 state arrays + probe accumulators
#define I_OFF  (16*CELLS)

typedef float v2f __attribute__((ext_vector_type(2)));

__device__ __forceinline__ float dpp_up1(float v) {   // lane i <- lane i-1
    int r = __builtin_amdgcn_update_dpp(0, __builtin_bit_cast(int, v),
                                        0x138, 0xf, 0xf, true); // wave_shr:1
    return __builtin_bit_cast(float, r);
}
__device__ __forceinline__ float dpp_dn1(float v) {   // lane i <- lane i+1
    int r = __builtin_amdgcn_update_dpp(0, __builtin_bit_cast(int, v),
                                        0x130, 0xf, 0xf, true); // wave_shl:1
    return __builtin_bit_cast(float, r);
}

__device__ __forceinline__ float pml_prof(int i) {
    int t;
    if (i <= 20)            t = 20 - i;
    else if (i >= NXY - 21) t = i - (NXY - 21);
    else                    return 0.0f;
    float u  = (float)t * 0.05f;
    float u2 = u * u;
    return 3.0f * u2 * u2;
}

__global__ __launch_bounds__(TPB, 1)
void wave_k(const float* __restrict__ x, const float* __restrict__ rho,
            float* __restrict__ ws, float* __restrict__ out) {
    cg::grid_group grid = cg::this_grid();

    // XCD-contiguous remap (bijective, 256 = 8 XCD x 32): halo neighbors
    // (bi +/- 3) land on the same XCD's L2.
    int blk = ((blockIdx.x & 7) << 5) | (blockIdx.x >> 3);
    int b  = blk / 64;                // batch
    int r_ = blk % 64;
    int bi = r_ >> 1, cj = r_ & 1;    // 32 row-tiles x 2 col-tiles
    int I0 = OUTR * bi - 17;          // window row origin (40 rows)
    int J0 = 96 * cj - 16;            // window col origin (128 cols)
    int t  = threadIdx.x;
    int w  = t >> 6;                  // wave 0..7, owns window rows [5w,5w+5)
    int l  = t & 63;                  // lane: local cols 2l, 2l+1
    int row0 = I0 + RPL * w;
    int gj   = J0 + 2 * l;

    // [parity][top/bot][slot 0..9][lane]; wave w writes slot w+1;
    // reads up from slot w, down from slot w+2; slots 0,9 stay zero.
    __shared__ v2f hb[2][2][NW + 2][64];
    __shared__ float xs[NSTEPS];
    for (int k = t; k < 2 * 2 * (NW + 2) * 64; k += TPB)
        ((v2f*)hb)[k] = (v2f){0.f, 0.f};
    if (t < NSTEPS) xs[t] = x[b * NSTEPS + t];   // this batch's source trace

    bool cok = (gj >= 0 && gj < NXY);

    // ---- K (=a1*c2/H2) and Q (=1-2*a1) computed once, in-register ----
    // Same formulas/op-order as the old setup_k. Lane-edge DPP zeros only
    // corrupt window cols 0 and 127, which never enter the clean region
    // [1,127) that the 16-step halo shrink needs.  Rows need no exchange:
    // each lane loads its own 7 rho rows.
    v2f Ka[RPL], Qa[RPL];
    {
        v2f rv[RPL + 2];
#pragma unroll
        for (int r = 0; r < RPL + 2; r++) {
            int gi = row0 - 1 + r;
            bool ok = cok && gi >= 0 && gi < NXY;
            rv[r] = ok ? *(const v2f*)(rho + gi * NXY + gj) : (v2f){0.f, 0.f};
        }
        const float IH2 = (float)(1.0 / (2.01 * 2.01));
#pragma unroll
        for (int r = 0; r < RPL; r++) {
            int gi = row0 + r;
            v2f rc = rv[r + 1], ru = rv[r], rd = rv[r + 2];
            float lf = dpp_up1(rc.y);             // left neighbor of .x
            float rt = dpp_dn1(rc.x);             // right neighbor of .y
            float bx = pml_prof(gi);
            v2f K, Q;
            {
                float lpf = 0.5f * rc.x + 0.125f * ((ru.x + rd.x) + (lf + rc.y));
                float p   = 0.5f * (1.0f + tanhf(100.0f * (lpf - 0.5f)));
                float c   = 1.0f - 0.1f * p;
                float by  = pml_prof(gj);
                float bb  = sqrtf(bx * bx + by * by);
                float a1  = 1.0f / (1.0f + 0.5f * bb);
                K.x = a1 * (c * c * IH2);
                Q.x = 1.0f - 2.0f * a1;
            }
            {
                float lpf = 0.5f * rc.y + 0.125f * ((ru.y + rd.y) + (rc.x + rt));
                float p   = 0.5f * (1.0f + tanhf(100.0f * (lpf - 0.5f)));
                float c   = 1.0f - 0.1f * p;
                float by  = pml_prof(gj + 1);
                float bb  = sqrtf(bx * bx + by * by);
                float a1  = 1.0f / (1.0f + 0.5f * bb);
                K.y = a1 * (c * c * IH2);
                Q.y = 1.0f - 2.0f * a1;
            }
            bool ok = cok && gi >= 0 && gi < NXY;
            Ka[r] = ok ? K : (v2f){0.f, 0.f};   // out-of-domain: K=Q=0 -> 0 forever
            Qa[r] = ok ? Q : (v2f){0.f, 0.f};
        }
    }

    // chunk-0 state is identically zero -> registers, no global zero-init,
    // and buffer parity guarantees write-before-read for every later chunk.
    v2f yc[RPL], yp[RPL];
#pragma unroll
    for (int r = 0; r < RPL; r++) { yc[r] = (v2f){0.f, 0.f}; yp[r] = (v2f){0.f, 0.f}; }

    // source (40,96): window col 96-J0 (112 for cj0, 16 for cj1) - always even
    int sr = 40 - I0, sc = 96 - J0;
    bool wave_src = (sr >= RPL * w) && (sr < RPL * w + RPL);
    int src_rl = sr - RPL * w;
    float srcm = (2 * l == sc) ? 1.f : 0.f;

    // probes (160,{48,96,144}): row 160 -> bi==26, window row 21 (wave 4, r=1)
    int pcl = 2 * l + J0;             // this lane's global .x column
    bool wave_prb = (bi == 26) && (w == 4);
    const int prb_rl = 1;
    bool is_prb = (cj == 0) ? (pcl == 48) : (pcl == 96 || pcl == 144);
    float prbm = is_prb ? 1.f : 0.f;
    float pacc = 0.f;                 // accumulates across ALL chunks

    v2f uph, dnh;
    __syncthreads();                  // hb zero-init + xs visible

// row update: yn = c + Q*(p-c) + K*(S-4c) — packed fp32, 2 DPP per 2 cells
#define ROWC(CUR, PRV, rr_, UP, DN, XSV, YN) do {                              \
    v2f cv = CUR[rr_];                                                         \
    float lf0 = dpp_up1(cv.y);                                                 \
    float rt1 = dpp_dn1(cv.x);                                                 \
    v2f h = (v2f){lf0, rt1} + __builtin_shufflevector(cv, cv, 1, 0);           \
    v2f S = ((UP) + (DN)) + h;                                                 \
    YN = cv + Qa[rr_] * (PRV[rr_] - cv) + Ka[rr_] * (S - 4.0f * cv);           \
    if (wave_src && (rr_) == src_rl) YN.x += srcm * (XSV);                     \
    if (wave_prb && (rr_) == prb_rl) { float q = prbm * YN.x; pacc += q * YN.x; } \
} while (0)

// boundary rows first (early LDS write), interior hides it; ghost read after
// barrier is first used next step
#define STEP(CUR, PRV, PH, SIDX) do {                                          \
    v2f t0, t4;                                                                \
    ROWC(CUR, PRV, 0, uph,    CUR[1], xv[SIDX], t0);                           \
    ROWC(CUR, PRV, 4, CUR[3], dnh,    xv[SIDX], t4);                           \
    hb[PH][0][w + 1][l] = t0;                                                  \
    hb[PH][1][w + 1][l] = t4;                                                  \
    PRV[0] = t0; PRV[4] = t4;                                                  \
    _Pragma("unroll")                                                          \
    for (int r = 1; r <= 3; r++) {                                             \
        v2f y;                                                                 \
        ROWC(CUR, PRV, r, CUR[r - 1], CUR[r + 1], xv[SIDX], y);                \
        PRV[r] = y;                                                            \
    }                                                                          \
    __syncthreads();                                                           \
    uph = hb[PH][1][w][l];                                                     \
    dnh = hb[PH][0][w + 2][l];                                                 \
} while (0)

#pragma unroll 1
    for (int chunk = 0; chunk < NCHUNK; chunk++) {
        // source amplitudes for this chunk (LDS broadcast -> registers)
        float xv[TCH];
#pragma unroll
        for (int i = 0; i < TCH; i++) xv[i] = xs[chunk * TCH + i];

        // reload the 40x128 state window (neighbors' halos changed);
        // chunk 0 keeps the zeroed registers.
        if (chunk) {
            int pin = chunk & 1;
            const float* curg = ws + ((pin * 2 + 0) * NBATCH + b) * CELLS;
            const float* prvg = ws + ((pin * 2 + 1) * NBATCH + b) * CELLS;
#pragma unroll
            for (int r = 0; r < RPL; r++) {
                int gi = row0 + r;
                bool ok = cok && gi >= 0 && gi < NXY;
                v2f cv = {0.f, 0.f}, pv = {0.f, 0.f};
                if (ok) {
                    int idx = gi * NXY + gj;
                    cv = *(const v2f*)(curg + idx);
                    pv = *(const v2f*)(prvg + idx);
                }
                yc[r] = cv; yp[r] = pv;
            }
        }

        // prologue halo exchange (parity 0)
        hb[0][0][w + 1][l] = yc[0];
        hb[0][1][w + 1][l] = yc[4];
        __syncthreads();
        uph = hb[0][1][w][l];
        dnh = hb[0][0][w + 2][l];

#pragma unroll
        for (int s2 = 0; s2 < TCH / 2; s2++) {
            STEP(yc, yp, 1, 2 * s2);        // new cur -> yp, writes hb[1]
            STEP(yp, yc, 0, 2 * s2 + 1);    // new cur -> yc, writes hb[0]
        }
        // yc = y(t_end), yp = y(t_end-1); clean on window rows [16,24), cols [16,112)

        if (chunk != NCHUNK - 1) {
            // store out-tile: rows [6bi,6bi+6) (window rows [17,23)), lanes 8..55
            int pout = (chunk & 1) ^ 1;
            float* ncurg = ws + ((pout * 2 + 0) * NBATCH + b) * CELLS;
            float* nprvg = ws + ((pout * 2 + 1) * NBATCH + b) * CELLS;
#pragma unroll
            for (int r = 0; r < RPL; r++) {
                int gi = row0 + r;
                if (gi >= OUTR * bi && gi < OUTR * bi + OUTR && l >= 8 && l < 56) {
                    int idx = gi * NXY + gj;
                    *(v2f*)(ncurg + idx) = yc[r];
                    *(v2f*)(nprvg + idx) = yp[r];
                }
            }
        } else {
            // last chunk: publish probe energy (unique writer per (b,pid))
            if (wave_prb && is_prb)
                ws[I_OFF + b * 3 + (pcl / 48 - 1)] = pacc;
        }

        grid.sync();   // release own tile / acquire neighbors' tiles
    }

    // last grid.sync() above orders probe writes before this read
    if (blockIdx.x == 0 && t < 12) {
        const float* I = ws + I_OFF;
        int bb = t / 3;
        float s = I[3 * bb] + I[3 * bb + 1] + I[3 * bb + 2];
        out[t] = I[t] / s;
    }
}
#undef STEP
#undef ROWC

extern "C" void kernel_launch(void* const* d_in, const int* in_sizes, int n_in,
                              void* d_out, int out_size, void* d_ws, size_t ws_size,
                              hipStream_t stream) {
    const float* x   = (const float*)d_in[0];   // (4,256) fp32
    const float* rho = (const float*)d_in[1];   // (192,192) fp32
    float* ws  = (float*)d_ws;
    float* outp = (float*)d_out;

    void* args[] = {(void*)&x, (void*)&rho, (void*)&ws, (void*)&outp};
    hipLaunchCooperativeKernel(wave_k, dim3(NBLKS), dim3(TPB), args, 0, stream);
}

// Round 2
// 485.607 us; speedup vs baseline: 1.2519x; 1.2519x over previous
//
#include <hip/hip_runtime.h>
#include <math.h>

#define NXY    192
#define CELLS  (NXY*NXY)
#define NBATCH 4
#define NSTEPS 256
#define TCH    16                 // steps per chunk (= halo radius)
#define NCHUNK (NSTEPS/TCH)       // 16
#define TPB    512                // 8 waves -> 2 waves/SIMD
#define NW     8
#define RPL    5                  // rows per wave (40-row window / 8 waves)
#define OUTR   6                  // out rows per tile
#define NBLKS  256                // 32 row-tiles x 2 col-tiles x 4 batches
// in-tile 128 cols x 40 rows; out-tile 96 cols x 6 rows (window rows [17,23))

// workspace layout (float offsets): 16 state arrays + probe area + flags
#define I_OFF   (16*CELLS)
#define FLG_OFF (I_OFF + 64)      // int flags[NBLKS], monotonic chunk counters

typedef float v2f __attribute__((ext_vector_type(2)));

__device__ __forceinline__ float dpp_up1(float v) {   // lane i <- lane i-1
    int r = __builtin_amdgcn_update_dpp(0, __builtin_bit_cast(int, v),
                                        0x138, 0xf, 0xf, true); // wave_shr:1
    return __builtin_bit_cast(float, r);
}
__device__ __forceinline__ float dpp_dn1(float v) {   // lane i <- lane i+1
    int r = __builtin_amdgcn_update_dpp(0, __builtin_bit_cast(int, v),
                                        0x130, 0xf, 0xf, true); // wave_shl:1
    return __builtin_bit_cast(float, r);
}

__device__ __forceinline__ float pml_prof(int i) {
    int t;
    if (i <= 20)            t = 20 - i;
    else if (i >= NXY - 21) t = i - (NXY - 21);
    else                    return 0.0f;
    float u  = (float)t * 0.05f;
    float u2 = u * u;
    return 3.0f * u2 * u2;
}

__global__ __launch_bounds__(TPB, 1)
void wave_k(const float* __restrict__ x, const float* __restrict__ rho,
            float* __restrict__ ws, float* __restrict__ out) {
    // XCD-contiguous remap (bijective, 256 = 8 XCD x 32)
    int blk = ((blockIdx.x & 7) << 5) | (blockIdx.x >> 3);
    int b  = blk / 64;                // batch
    int r_ = blk % 64;
    int bi = r_ >> 1, cj = r_ & 1;    // 32 row-tiles x 2 col-tiles
    int I0 = OUTR * bi - 17;          // window row origin (40 rows)
    int J0 = 96 * cj - 16;            // window col origin (128 cols)
    int t  = threadIdx.x;
    int w  = t >> 6;                  // wave 0..7, owns window rows [5w,5w+5)
    int l  = t & 63;                  // lane: local cols 2l, 2l+1
    int row0 = I0 + RPL * w;
    int gj   = J0 + 2 * l;

    int* flags = (int*)(ws + FLG_OFF);
    // dependency set: row-tiles bi-3..bi+3 (clamped), both col-tiles, same b.
    // Symmetric relation -> also protects WAR on the parity buffers.
    int drt = bi + (t >> 1) - 3;
    int dfi = b * 64 + drt * 2 + (t & 1);
    bool dvalid = (t < 14) && (drt >= 0) && (drt < 32);

    // [parity][top/bot][slot 0..9][lane]; wave w writes slot w+1;
    // reads up from slot w, down from slot w+2; slots 0,9 stay zero.
    __shared__ v2f hb[2][2][NW + 2][64];
    __shared__ float xs[NSTEPS];
    for (int k = t; k < 2 * 2 * (NW + 2) * 64; k += TPB)
        ((v2f*)hb)[k] = (v2f){0.f, 0.f};
    if (t < NSTEPS) xs[t] = x[b * NSTEPS + t];   // this batch's source trace

    bool cok = (gj >= 0 && gj < NXY);

    // ---- K (=a1*c2/H2) and Q (=1-2*a1) computed once, in-register ----
    // (verified in round 1; lane-edge DPP zeros only touch window cols 0/127,
    // outside the clean region)
    v2f Ka[RPL], Qa[RPL];
    {
        v2f rv[RPL + 2];
#pragma unroll
        for (int r = 0; r < RPL + 2; r++) {
            int gi = row0 - 1 + r;
            bool ok = cok && gi >= 0 && gi < NXY;
            rv[r] = ok ? *(const v2f*)(rho + gi * NXY + gj) : (v2f){0.f, 0.f};
        }
        const float IH2 = (float)(1.0 / (2.01 * 2.01));
#pragma unroll
        for (int r = 0; r < RPL; r++) {
            int gi = row0 + r;
            v2f rc = rv[r + 1], ru = rv[r], rd = rv[r + 2];
            float lf = dpp_up1(rc.y);
            float rt = dpp_dn1(rc.x);
            float bx = pml_prof(gi);
            v2f K, Q;
            {
                float lpf = 0.5f * rc.x + 0.125f * ((ru.x + rd.x) + (lf + rc.y));
                float p   = 0.5f * (1.0f + tanhf(100.0f * (lpf - 0.5f)));
                float c   = 1.0f - 0.1f * p;
                float by  = pml_prof(gj);
                float bb  = sqrtf(bx * bx + by * by);
                float a1  = 1.0f / (1.0f + 0.5f * bb);
                K.x = a1 * (c * c * IH2);
                Q.x = 1.0f - 2.0f * a1;
            }
            {
                float lpf = 0.5f * rc.y + 0.125f * ((ru.y + rd.y) + (rc.x + rt));
                float p   = 0.5f * (1.0f + tanhf(100.0f * (lpf - 0.5f)));
                float c   = 1.0f - 0.1f * p;
                float by  = pml_prof(gj + 1);
                float bb  = sqrtf(bx * bx + by * by);
                float a1  = 1.0f / (1.0f + 0.5f * bb);
                K.y = a1 * (c * c * IH2);
                Q.y = 1.0f - 2.0f * a1;
            }
            bool ok = cok && gi >= 0 && gi < NXY;
            Ka[r] = ok ? K : (v2f){0.f, 0.f};   // out-of-domain: K=Q=0 -> 0 forever
            Qa[r] = ok ? Q : (v2f){0.f, 0.f};
        }
    }

    // chunk-0 state is identically zero -> registers; buffer parity
    // guarantees write-before-read for every later chunk.
    v2f yc[RPL], yp[RPL];
#pragma unroll
    for (int r = 0; r < RPL; r++) { yc[r] = (v2f){0.f, 0.f}; yp[r] = (v2f){0.f, 0.f}; }

    // source (40,96): window col 96-J0 - always even
    int sr = 40 - I0, sc = 96 - J0;
    bool wave_src = (sr >= RPL * w) && (sr < RPL * w + RPL);
    int src_rl = sr - RPL * w;
    float srcm = (2 * l == sc) ? 1.f : 0.f;

    // probes (160,{48,96,144}): row 160 -> bi==26, window row 21 (wave 4, r=1)
    int pcl = 2 * l + J0;             // this lane's global .x column
    bool wave_prb = (bi == 26) && (w == 4);
    const int prb_rl = 1;
    bool is_prb = (cj == 0) ? (pcl == 48) : (pcl == 96 || pcl == 144);
    float prbm = is_prb ? 1.f : 0.f;
    float pacc = 0.f;                 // accumulates across ALL chunks

    v2f uph, dnh;
    __syncthreads();                  // hb zero-init + xs visible

// row update: yn = c + Q*(p-c) + K*(S-4c) — packed fp32, 2 DPP per 2 cells
#define ROWC(CUR, PRV, rr_, UP, DN, XSV, YN) do {                              \
    v2f cv = CUR[rr_];                                                         \
    float lf0 = dpp_up1(cv.y);                                                 \
    float rt1 = dpp_dn1(cv.x);                                                 \
    v2f h = (v2f){lf0, rt1} + __builtin_shufflevector(cv, cv, 1, 0);           \
    v2f S = ((UP) + (DN)) + h;                                                 \
    YN = cv + Qa[rr_] * (PRV[rr_] - cv) + Ka[rr_] * (S - 4.0f * cv);           \
    if (wave_src && (rr_) == src_rl) YN.x += srcm * (XSV);                     \
    if (wave_prb && (rr_) == prb_rl) { float q = prbm * YN.x; pacc += q * YN.x; } \
} while (0)

#define STEP(CUR, PRV, PH, SIDX) do {                                          \
    v2f t0, t4;                                                                \
    ROWC(CUR, PRV, 0, uph,    CUR[1], xv[SIDX], t0);                           \
    ROWC(CUR, PRV, 4, CUR[3], dnh,    xv[SIDX], t4);                           \
    hb[PH][0][w + 1][l] = t0;                                                  \
    hb[PH][1][w + 1][l] = t4;                                                  \
    PRV[0] = t0; PRV[4] = t4;                                                  \
    _Pragma("unroll")                                                          \
    for (int r = 1; r <= 3; r++) {                                             \
        v2f y;                                                                 \
        ROWC(CUR, PRV, r, CUR[r - 1], CUR[r + 1], xv[SIDX], y);                \
        PRV[r] = y;                                                            \
    }                                                                          \
    __syncthreads();                                                           \
    uph = hb[PH][1][w][l];                                                     \
    dnh = hb[PH][0][w + 2][l];                                                 \
} while (0)

#pragma unroll 1
    for (int chunk = 0; chunk < NCHUNK; chunk++) {
        // source amplitudes for this chunk (LDS broadcast -> registers)
        float xv[TCH];
#pragma unroll
        for (int i = 0; i < TCH; i++) xv[i] = xs[chunk * TCH + i];

        if (chunk) {
            // wait for the <=14 producer blocks to finish chunk-1
            if (dvalid) {
                while (__hip_atomic_load(&flags[dfi], __ATOMIC_RELAXED,
                                         __HIP_MEMORY_SCOPE_AGENT) < chunk) {}
            }
            __syncthreads();
            // per-wave acquire: invalidate stale L2 before halo reads.
            // Cross-chunk working set is registers+LDS, so the inv is ~free.
            __builtin_amdgcn_fence(__ATOMIC_ACQUIRE, "agent");

            int pin = chunk & 1;
            const float* curg = ws + ((pin * 2 + 0) * NBATCH + b) * CELLS;
            const float* prvg = ws + ((pin * 2 + 1) * NBATCH + b) * CELLS;
#pragma unroll
            for (int r = 0; r < RPL; r++) {
                int gi = row0 + r;
                bool ok = cok && gi >= 0 && gi < NXY;
                v2f cv = {0.f, 0.f}, pv = {0.f, 0.f};
                if (ok) {
                    int idx = gi * NXY + gj;
                    cv = *(const v2f*)(curg + idx);
                    pv = *(const v2f*)(prvg + idx);
                }
                yc[r] = cv; yp[r] = pv;
            }
        }

        // prologue halo exchange (parity 0)
        hb[0][0][w + 1][l] = yc[0];
        hb[0][1][w + 1][l] = yc[4];
        __syncthreads();
        uph = hb[0][1][w][l];
        dnh = hb[0][0][w + 2][l];

#pragma unroll
        for (int s2 = 0; s2 < TCH / 2; s2++) {
            STEP(yc, yp, 1, 2 * s2);        // new cur -> yp, writes hb[1]
            STEP(yp, yc, 0, 2 * s2 + 1);    // new cur -> yc, writes hb[0]
        }
        // yc = y(t_end), yp = y(t_end-1); clean on window rows [16,24), cols [16,112)

        if (chunk != NCHUNK - 1) {
            // store out-tile: rows [6bi,6bi+6) (window rows [17,23)), lanes 8..55
            int pout = (chunk & 1) ^ 1;
            float* ncurg = ws + ((pout * 2 + 0) * NBATCH + b) * CELLS;
            float* nprvg = ws + ((pout * 2 + 1) * NBATCH + b) * CELLS;
#pragma unroll
            for (int r = 0; r < RPL; r++) {
                int gi = row0 + r;
                if (gi >= OUTR * bi && gi < OUTR * bi + OUTR && l >= 8 && l < 56) {
                    int idx = gi * NXY + gj;
                    *(v2f*)(ncurg + idx) = yc[r];
                    *(v2f*)(nprvg + idx) = yp[r];
                }
            }
        } else {
            // last chunk: publish probe energy (unique writer per (b,pid))
            if (wave_prb && is_prb)
                ws[I_OFF + b * 3 + (pcl / 48 - 1)] = pacc;
        }

        // release: all waves' stores drained (syncthreads waits vmcnt),
        // then writeback L2 + publish flag at agent scope.
        __syncthreads();
        if (t == 0) {
            __builtin_amdgcn_fence(__ATOMIC_RELEASE, "agent");
            __hip_atomic_store(&flags[blk], chunk + 1, __ATOMIC_RELAXED,
                               __HIP_MEMORY_SCOPE_AGENT);
        }
    }
#undef STEP
#undef ROWC

    // finalization: block 0 waits for the 8 probe-owning blocks
    // (blk = b*64 + 26*2 + cj), then normalizes.
    if (blk == 0) {
        if (t < 8) {
            int pb = (t >> 1) * 64 + 52 + (t & 1);
            while (__hip_atomic_load(&flags[pb], __ATOMIC_RELAXED,
                                     __HIP_MEMORY_SCOPE_AGENT) < NCHUNK) {}
        }
        __syncthreads();
        __builtin_amdgcn_fence(__ATOMIC_ACQUIRE, "agent");
        if (t < 12) {
            const float* I = ws + I_OFF;
            int bb = t / 3;
            float s = I[3 * bb] + I[3 * bb + 1] + I[3 * bb + 2];
            out[t] = I[t] / s;
        }
    }
}

extern "C" void kernel_launch(void* const* d_in, const int* in_sizes, int n_in,
                              void* d_out, int out_size, void* d_ws, size_t ws_size,
                              hipStream_t stream) {
    const float* x   = (const float*)d_in[0];   // (4,256) fp32
    const float* rho = (const float*)d_in[1];   // (192,192) fp32
    float* ws  = (float*)d_ws;
    float* outp = (float*)d_out;

    // zero the probe area + flags (poisoned between iterations)
    hipMemsetAsync((char*)d_ws + I_OFF * sizeof(float), 0,
                   (64 + NBLKS) * sizeof(float), stream);

    void* args[] = {(void*)&x, (void*)&rho, (void*)&ws, (void*)&outp};
    // cooperative launch only for the co-residency guarantee (no grid.sync)
    hipLaunchCooperativeKernel(wave_k, dim3(NBLKS), dim3(TPB), args, 0, stream);
}

// Round 3
// 215.087 us; speedup vs baseline: 2.8265x; 2.2577x over previous
//
#include <hip/hip_runtime.h>
#include <math.h>

#define NXY    192
#define CELLS  (NXY*NXY)
#define NBATCH 4
#define NSTEPS 256
#define TCH    16                 // steps per chunk (= halo radius)
#define NCHUNK (NSTEPS/TCH)       // 16
#define TPB    512                // 8 waves -> 2 waves/SIMD
#define NW     8
#define RPL    5                  // rows per wave (40-row window / 8 waves)
#define OUTR   6                  // out rows per tile
#define NBLKS  256                // 32 row-tiles x 2 col-tiles x 4 batches
// in-tile 128 cols x 40 rows; out-tile 96 cols x 6 rows (window rows [17,23))

// workspace layout (float offsets): 16 state arrays + probe area + flags
#define I_OFF   (16*CELLS)
#define FLG_OFF (I_OFF + 64)      // int flags[NBLKS], monotonic chunk counters

typedef float v2f __attribute__((ext_vector_type(2)));

__device__ __forceinline__ float dpp_up1(float v) {   // lane i <- lane i-1
    int r = __builtin_amdgcn_update_dpp(0, __builtin_bit_cast(int, v),
                                        0x138, 0xf, 0xf, true); // wave_shr:1
    return __builtin_bit_cast(float, r);
}
__device__ __forceinline__ float dpp_dn1(float v) {   // lane i <- lane i+1
    int r = __builtin_amdgcn_update_dpp(0, __builtin_bit_cast(int, v),
                                        0x130, 0xf, 0xf, true); // wave_shl:1
    return __builtin_bit_cast(float, r);
}

__device__ __forceinline__ float pml_prof(int i) {
    int t;
    if (i <= 20)            t = 20 - i;
    else if (i >= NXY - 21) t = i - (NXY - 21);
    else                    return 0.0f;
    float u  = (float)t * 0.05f;
    float u2 = u * u;
    return 3.0f * u2 * u2;
}

__global__ __launch_bounds__(TPB, 1)
void wave_k(const float* __restrict__ x, const float* __restrict__ rho,
            float* __restrict__ ws, float* __restrict__ out) {
    // XCD-contiguous remap (bijective, 256 = 8 XCD x 32)
    int blk = ((blockIdx.x & 7) << 5) | (blockIdx.x >> 3);
    int b  = blk / 64;                // batch
    int r_ = blk % 64;
    int bi = r_ >> 1, cj = r_ & 1;    // 32 row-tiles x 2 col-tiles
    int I0 = OUTR * bi - 17;          // window row origin (40 rows)
    int J0 = 96 * cj - 16;            // window col origin (128 cols)
    int t  = threadIdx.x;
    int w  = t >> 6;                  // wave 0..7, owns window rows [5w,5w+5)
    int l  = t & 63;                  // lane: local cols 2l, 2l+1
    int row0 = I0 + RPL * w;
    int gj   = J0 + 2 * l;

    int* flags = (int*)(ws + FLG_OFF);
    // dependency set: row-tiles bi-3..bi+3 (clamped), both col-tiles, same b.
    // Symmetric relation -> also protects WAR on the parity buffers.
    // Only wave 0 polls (t<14).
    int drt = bi + (t >> 1) - 3;
    int dfi = b * 64 + drt * 2 + (t & 1);
    bool dvalid = (t < 14) && (drt >= 0) && (drt < 32);

    // [parity][top/bot][slot 0..9][lane]; wave w writes slot w+1;
    // reads up from slot w, down from slot w+2; slots 0,9 stay zero.
    __shared__ v2f hb[2][2][NW + 2][64];
    __shared__ float xs[NSTEPS];
    for (int k = t; k < 2 * 2 * (NW + 2) * 64; k += TPB)
        ((v2f*)hb)[k] = (v2f){0.f, 0.f};
    if (t < NSTEPS) xs[t] = x[b * NSTEPS + t];   // this batch's source trace

    bool cok = (gj >= 0 && gj < NXY);

    // ---- K (=a1*c2/H2) and Q (=1-2*a1) computed once, in-register ----
    // (verified: lane-edge DPP zeros only touch window cols 0/127,
    // outside the clean region)
    v2f Ka[RPL], Qa[RPL];
    {
        v2f rv[RPL + 2];
#pragma unroll
        for (int r = 0; r < RPL + 2; r++) {
            int gi = row0 - 1 + r;
            bool ok = cok && gi >= 0 && gi < NXY;
            rv[r] = ok ? *(const v2f*)(rho + gi * NXY + gj) : (v2f){0.f, 0.f};
        }
        const float IH2 = (float)(1.0 / (2.01 * 2.01));
#pragma unroll
        for (int r = 0; r < RPL; r++) {
            int gi = row0 + r;
            v2f rc = rv[r + 1], ru = rv[r], rd = rv[r + 2];
            float lf = dpp_up1(rc.y);
            float rt = dpp_dn1(rc.x);
            float bx = pml_prof(gi);
            v2f K, Q;
            {
                float lpf = 0.5f * rc.x + 0.125f * ((ru.x + rd.x) + (lf + rc.y));
                float p   = 0.5f * (1.0f + tanhf(100.0f * (lpf - 0.5f)));
                float c   = 1.0f - 0.1f * p;
                float by  = pml_prof(gj);
                float bb  = sqrtf(bx * bx + by * by);
                float a1  = 1.0f / (1.0f + 0.5f * bb);
                K.x = a1 * (c * c * IH2);
                Q.x = 1.0f - 2.0f * a1;
            }
            {
                float lpf = 0.5f * rc.y + 0.125f * ((ru.y + rd.y) + (rc.x + rt));
                float p   = 0.5f * (1.0f + tanhf(100.0f * (lpf - 0.5f)));
                float c   = 1.0f - 0.1f * p;
                float by  = pml_prof(gj + 1);
                float bb  = sqrtf(bx * bx + by * by);
                float a1  = 1.0f / (1.0f + 0.5f * bb);
                K.y = a1 * (c * c * IH2);
                Q.y = 1.0f - 2.0f * a1;
            }
            bool ok = cok && gi >= 0 && gi < NXY;
            Ka[r] = ok ? K : (v2f){0.f, 0.f};   // out-of-domain: K=Q=0 -> 0 forever
            Qa[r] = ok ? Q : (v2f){0.f, 0.f};
        }
    }

    // chunk-0 state is identically zero -> registers; buffer parity
    // guarantees write-before-read for every later chunk.
    v2f yc[RPL], yp[RPL];
#pragma unroll
    for (int r = 0; r < RPL; r++) { yc[r] = (v2f){0.f, 0.f}; yp[r] = (v2f){0.f, 0.f}; }

    // source (40,96): window col 96-J0 - always even
    int sr = 40 - I0, sc = 96 - J0;
    bool wave_src = (sr >= RPL * w) && (sr < RPL * w + RPL);
    int src_rl = sr - RPL * w;
    float srcm = (2 * l == sc) ? 1.f : 0.f;

    // probes (160,{48,96,144}): row 160 -> bi==26, window row 21 (wave 4, r=1)
    int pcl = 2 * l + J0;             // this lane's global .x column
    bool wave_prb = (bi == 26) && (w == 4);
    const int prb_rl = 1;
    bool is_prb = (cj == 0) ? (pcl == 48) : (pcl == 96 || pcl == 144);
    float prbm = is_prb ? 1.f : 0.f;
    float pacc = 0.f;                 // accumulates across ALL chunks

    v2f uph, dnh;
    __syncthreads();                  // hb zero-init + xs visible

// row update: yn = c + Q*(p-c) + K*(S-4c) — packed fp32, 2 DPP per 2 cells
#define ROWC(CUR, PRV, rr_, UP, DN, XSV, YN) do {                              \
    v2f cv = CUR[rr_];                                                         \
    float lf0 = dpp_up1(cv.y);                                                 \
    float rt1 = dpp_dn1(cv.x);                                                 \
    v2f h = (v2f){lf0, rt1} + __builtin_shufflevector(cv, cv, 1, 0);           \
    v2f S = ((UP) + (DN)) + h;                                                 \
    YN = cv + Qa[rr_] * (PRV[rr_] - cv) + Ka[rr_] * (S - 4.0f * cv);           \
    if (wave_src && (rr_) == src_rl) YN.x += srcm * (XSV);                     \
    if (wave_prb && (rr_) == prb_rl) { float q = prbm * YN.x; pacc += q * YN.x; } \
} while (0)

#define STEP(CUR, PRV, PH, SIDX) do {                                          \
    v2f t0, t4;                                                                \
    ROWC(CUR, PRV, 0, uph,    CUR[1], xv[SIDX], t0);                           \
    ROWC(CUR, PRV, 4, CUR[3], dnh,    xv[SIDX], t4);                           \
    hb[PH][0][w + 1][l] = t0;                                                  \
    hb[PH][1][w + 1][l] = t4;                                                  \
    PRV[0] = t0; PRV[4] = t4;                                                  \
    _Pragma("unroll")                                                          \
    for (int r = 1; r <= 3; r++) {                                             \
        v2f y;                                                                 \
        ROWC(CUR, PRV, r, CUR[r - 1], CUR[r + 1], xv[SIDX], y);                \
        PRV[r] = y;                                                            \
    }                                                                          \
    __syncthreads();                                                           \
    uph = hb[PH][1][w][l];                                                     \
    dnh = hb[PH][0][w + 2][l];                                                 \
} while (0)

#pragma unroll 1
    for (int chunk = 0; chunk < NCHUNK; chunk++) {
        // source amplitudes for this chunk (LDS broadcast -> registers)
        float xv[TCH];
#pragma unroll
        for (int i = 0; i < TCH; i++) xv[i] = xs[chunk * TCH + i];

        if (chunk) {
            // wait for the <=14 producer blocks to finish chunk-1
            // (agent-scope poll: sc1 load, bypasses non-coherent L2)
            if (dvalid) {
                while (__hip_atomic_load(&flags[dfi], __ATOMIC_RELAXED,
                                         __HIP_MEMORY_SCOPE_AGENT) < chunk) {}
            }
            __syncthreads();

            // reload the 40x128 state window. All producer stores were sc0 sc1
            // (visible at the coherent point = Infinity Cache), so plain
            // coherent loads suffice — NO cache-maintenance fence needed.
            int pin = chunk & 1;
            const float* curg = ws + ((pin * 2 + 0) * NBATCH + b) * CELLS;
            const float* prvg = ws + ((pin * 2 + 1) * NBATCH + b) * CELLS;
            int  idxr[RPL];
            bool okr[RPL];
#pragma unroll
            for (int r = 0; r < RPL; r++) {
                int gi = row0 + r;
                okr[r]  = cok && gi >= 0 && gi < NXY;
                idxr[r] = okr[r] ? gi * NXY + gj : 0;   // safe dummy addr
            }
            v2f c0, c1, c2, c3, c4, p0, p1, p2, p3, p4;
            asm volatile(
                "global_load_dwordx2 %0, %10, off sc0 sc1\n\t"
                "global_load_dwordx2 %1, %11, off sc0 sc1\n\t"
                "global_load_dwordx2 %2, %12, off sc0 sc1\n\t"
                "global_load_dwordx2 %3, %13, off sc0 sc1\n\t"
                "global_load_dwordx2 %4, %14, off sc0 sc1\n\t"
                "global_load_dwordx2 %5, %15, off sc0 sc1\n\t"
                "global_load_dwordx2 %6, %16, off sc0 sc1\n\t"
                "global_load_dwordx2 %7, %17, off sc0 sc1\n\t"
                "global_load_dwordx2 %8, %18, off sc0 sc1\n\t"
                "global_load_dwordx2 %9, %19, off sc0 sc1\n\t"
                "s_waitcnt vmcnt(0)"
                : "=&v"(c0), "=&v"(c1), "=&v"(c2), "=&v"(c3), "=&v"(c4),
                  "=&v"(p0), "=&v"(p1), "=&v"(p2), "=&v"(p3), "=&v"(p4)
                : "v"(curg + idxr[0]), "v"(curg + idxr[1]), "v"(curg + idxr[2]),
                  "v"(curg + idxr[3]), "v"(curg + idxr[4]),
                  "v"(prvg + idxr[0]), "v"(prvg + idxr[1]), "v"(prvg + idxr[2]),
                  "v"(prvg + idxr[3]), "v"(prvg + idxr[4])
                : "memory");
            yc[0] = okr[0] ? c0 : (v2f){0.f, 0.f};
            yc[1] = okr[1] ? c1 : (v2f){0.f, 0.f};
            yc[2] = okr[2] ? c2 : (v2f){0.f, 0.f};
            yc[3] = okr[3] ? c3 : (v2f){0.f, 0.f};
            yc[4] = okr[4] ? c4 : (v2f){0.f, 0.f};
            yp[0] = okr[0] ? p0 : (v2f){0.f, 0.f};
            yp[1] = okr[1] ? p1 : (v2f){0.f, 0.f};
            yp[2] = okr[2] ? p2 : (v2f){0.f, 0.f};
            yp[3] = okr[3] ? p3 : (v2f){0.f, 0.f};
            yp[4] = okr[4] ? p4 : (v2f){0.f, 0.f};
        }

        // prologue halo exchange (parity 0)
        hb[0][0][w + 1][l] = yc[0];
        hb[0][1][w + 1][l] = yc[4];
        __syncthreads();
        uph = hb[0][1][w][l];
        dnh = hb[0][0][w + 2][l];

#pragma unroll
        for (int s2 = 0; s2 < TCH / 2; s2++) {
            STEP(yc, yp, 1, 2 * s2);        // new cur -> yp, writes hb[1]
            STEP(yp, yc, 0, 2 * s2 + 1);    // new cur -> yc, writes hb[0]
        }
        // yc = y(t_end), yp = y(t_end-1); clean on window rows [16,24), cols [16,112)

        if (chunk != NCHUNK - 1) {
            // store out-tile coherently (sc0 sc1 -> Infinity Cache):
            // rows [6bi,6bi+6) (window rows [17,23)), lanes 8..55
            int pout = (chunk & 1) ^ 1;
            float* ncurg = ws + ((pout * 2 + 0) * NBATCH + b) * CELLS;
            float* nprvg = ws + ((pout * 2 + 1) * NBATCH + b) * CELLS;
#pragma unroll
            for (int r = 0; r < RPL; r++) {
                int gi = row0 + r;
                if (gi >= OUTR * bi && gi < OUTR * bi + OUTR && l >= 8 && l < 56) {
                    int idx = gi * NXY + gj;
                    asm volatile(
                        "global_store_dwordx2 %0, %2, off sc0 sc1\n\t"
                        "global_store_dwordx2 %1, %3, off sc0 sc1"
                        :: "v"(ncurg + idx), "v"(nprvg + idx),
                           "v"(yc[r]), "v"(yp[r])
                        : "memory");
                }
            }
        } else {
            // last chunk: publish probe energy (unique writer per (b,pid))
            if (wave_prb && is_prb) {
                float* ip = ws + I_OFF + b * 3 + (pcl / 48 - 1);
                asm volatile("global_store_dword %0, %1, off sc0 sc1"
                             :: "v"(ip), "v"(pacc) : "memory");
            }
        }

        // release: drain this wave's coherent stores (compiler can't see the
        // asm stores' vmcnt), barrier (all waves drained), then publish flag
        // at agent scope. No wbl2 needed — data already at coherent point.
        asm volatile("s_waitcnt vmcnt(0)" ::: "memory");
        __syncthreads();
        if (t == 0) {
            __hip_atomic_store(&flags[blk], chunk + 1, __ATOMIC_RELAXED,
                               __HIP_MEMORY_SCOPE_AGENT);
        }
    }
#undef STEP
#undef ROWC

    // finalization: block 0 waits for the 8 probe-owning blocks
    // (blk = b*64 + 26*2 + cj), then normalizes. I[] reads agent-coherent.
    if (blk == 0) {
        if (t < 8) {
            int pb = (t >> 1) * 64 + 52 + (t & 1);
            while (__hip_atomic_load(&flags[pb], __ATOMIC_RELAXED,
                                     __HIP_MEMORY_SCOPE_AGENT) < NCHUNK) {}
        }
        __syncthreads();
        if (t < 12) {
            const float* I = ws + I_OFF;
            int bb = t / 3;
            float s = 0.f;
#pragma unroll
            for (int k = 0; k < 3; k++)
                s += __hip_atomic_load(I + 3 * bb + k, __ATOMIC_RELAXED,
                                       __HIP_MEMORY_SCOPE_AGENT);
            float num = __hip_atomic_load(I + t, __ATOMIC_RELAXED,
                                          __HIP_MEMORY_SCOPE_AGENT);
            out[t] = num / s;
        }
    }
}

extern "C" void kernel_launch(void* const* d_in, const int* in_sizes, int n_in,
                              void* d_out, int out_size, void* d_ws, size_t ws_size,
                              hipStream_t stream) {
    const float* x   = (const float*)d_in[0];   // (4,256) fp32
    const float* rho = (const float*)d_in[1];   // (192,192) fp32
    float* ws  = (float*)d_ws;
    float* outp = (float*)d_out;

    // zero the probe area + flags (poisoned between iterations)
    hipMemsetAsync((char*)d_ws + I_OFF * sizeof(float), 0,
                   (64 + NBLKS) * sizeof(float), stream);

    void* args[] = {(void*)&x, (void*)&rho, (void*)&ws, (void*)&outp};
    // cooperative launch only for the co-residency guarantee (no grid.sync)
    hipLaunchCooperativeKernel(wave_k, dim3(NBLKS), dim3(TPB), args, 0, stream);
}

// Round 4
// 207.520 us; speedup vs baseline: 2.9295x; 1.0365x over previous
//
#include <hip/hip_runtime.h>
#include <math.h>

#define NXY    192
#define CELLS  (NXY*NXY)
#define NBATCH 4
#define NSTEPS 256
#define TCH    16                 // steps per chunk (= halo radius)
#define NCHUNK (NSTEPS/TCH)       // 16
#define TPB    512                // 8 waves -> 2 waves/SIMD
#define NW     8
#define RPL    5                  // rows per wave (40-row window / 8 waves)
#define OUTR   6                  // out rows per tile
#define NBLKS  256                // 32 row-tiles x 2 col-tiles x 4 batches
// in-tile 128 cols x 40 rows; out-tile 96 cols x 6 rows (window rows [17,23))

// workspace layout (float offsets): 16 state arrays + probe area + flags
#define I_OFF   (16*CELLS)
#define FLG_OFF (I_OFF + 64)      // int flags[NBLKS]: counting (2 per chunk)

typedef float v2f __attribute__((ext_vector_type(2)));

__device__ __forceinline__ float dpp_up1(float v) {   // lane i <- lane i-1
    int r = __builtin_amdgcn_update_dpp(0, __builtin_bit_cast(int, v),
                                        0x138, 0xf, 0xf, true); // wave_shr:1
    return __builtin_bit_cast(float, r);
}
__device__ __forceinline__ float dpp_dn1(float v) {   // lane i <- lane i+1
    int r = __builtin_amdgcn_update_dpp(0, __builtin_bit_cast(int, v),
                                        0x130, 0xf, 0xf, true); // wave_shl:1
    return __builtin_bit_cast(float, r);
}

__device__ __forceinline__ float pml_prof(int i) {
    int t;
    if (i <= 20)            t = 20 - i;
    else if (i >= NXY - 21) t = i - (NXY - 21);
    else                    return 0.0f;
    float u  = (float)t * 0.05f;
    float u2 = u * u;
    return 3.0f * u2 * u2;
}

// Plain (non-cooperative) launch: co-residency is guaranteed by capacity —
// VGPR 56 -> 32 waves/CU, LDS 21.5KB -> 4 blocks/CU, so capacity >= 1024
// blocks for a 256-block grid; every block is resident before any spin.
__global__ __launch_bounds__(TPB, 1)
void wave_k(const float* __restrict__ x, const float* __restrict__ rho,
            float* __restrict__ ws, float* __restrict__ out) {
    // XCD-contiguous remap (bijective, 256 = 8 XCD x 32)
    int blk = ((blockIdx.x & 7) << 5) | (blockIdx.x >> 3);
    int b  = blk / 64;                // batch
    int r_ = blk % 64;
    int bi = r_ >> 1, cj = r_ & 1;    // 32 row-tiles x 2 col-tiles
    int I0 = OUTR * bi - 17;          // window row origin (40 rows)
    int J0 = 96 * cj - 16;            // window col origin (128 cols)
    int t  = threadIdx.x;
    int w  = t >> 6;                  // wave 0..7, owns window rows [5w,5w+5)
    int l  = t & 63;                  // lane: local cols 2l, 2l+1
    int row0 = I0 + RPL * w;
    int gj   = J0 + 2 * l;

    int* flags = (int*)(ws + FLG_OFF);
    // dependency set: row-tiles bi-3..bi+3 (clamped), both col-tiles, same b.
    // Symmetric relation -> also protects WAR on the parity buffers.
    // Only wave 0 polls (t<14).
    int drt = bi + (t >> 1) - 3;
    int dfi = b * 64 + drt * 2 + (t & 1);
    bool dvalid = (t < 14) && (drt >= 0) && (drt < 32);

    // [parity][top/bot][slot 0..9][lane]; wave w writes slot w+1;
    // reads up from slot w, down from slot w+2; slots 0,9 stay zero.
    __shared__ v2f hb[2][2][NW + 2][64];
    __shared__ float xs[NSTEPS];
    for (int k = t; k < 2 * 2 * (NW + 2) * 64; k += TPB)
        ((v2f*)hb)[k] = (v2f){0.f, 0.f};
    if (t < NSTEPS) xs[t] = x[b * NSTEPS + t];   // this batch's source trace

    bool cok = (gj >= 0 && gj < NXY);

    // ---- K (=a1*c2/H2) and Q (=1-2*a1) computed once, in-register ----
    // (verified: lane-edge DPP zeros only touch window cols 0/127,
    // outside the clean region)
    v2f Ka[RPL], Qa[RPL];
    {
        v2f rv[RPL + 2];
#pragma unroll
        for (int r = 0; r < RPL + 2; r++) {
            int gi = row0 - 1 + r;
            bool ok = cok && gi >= 0 && gi < NXY;
            rv[r] = ok ? *(const v2f*)(rho + gi * NXY + gj) : (v2f){0.f, 0.f};
        }
        const float IH2 = (float)(1.0 / (2.01 * 2.01));
#pragma unroll
        for (int r = 0; r < RPL; r++) {
            int gi = row0 + r;
            v2f rc = rv[r + 1], ru = rv[r], rd = rv[r + 2];
            float lf = dpp_up1(rc.y);
            float rt = dpp_dn1(rc.x);
            float bx = pml_prof(gi);
            v2f K, Q;
            {
                float lpf = 0.5f * rc.x + 0.125f * ((ru.x + rd.x) + (lf + rc.y));
                float p   = 0.5f * (1.0f + tanhf(100.0f * (lpf - 0.5f)));
                float c   = 1.0f - 0.1f * p;
                float by  = pml_prof(gj);
                float bb  = sqrtf(bx * bx + by * by);
                float a1  = 1.0f / (1.0f + 0.5f * bb);
                K.x = a1 * (c * c * IH2);
                Q.x = 1.0f - 2.0f * a1;
            }
            {
                float lpf = 0.5f * rc.y + 0.125f * ((ru.y + rd.y) + (rc.x + rt));
                float p   = 0.5f * (1.0f + tanhf(100.0f * (lpf - 0.5f)));
                float c   = 1.0f - 0.1f * p;
                float by  = pml_prof(gj + 1);
                float bb  = sqrtf(bx * bx + by * by);
                float a1  = 1.0f / (1.0f + 0.5f * bb);
                K.y = a1 * (c * c * IH2);
                Q.y = 1.0f - 2.0f * a1;
            }
            bool ok = cok && gi >= 0 && gi < NXY;
            Ka[r] = ok ? K : (v2f){0.f, 0.f};   // out-of-domain: K=Q=0 -> 0 forever
            Qa[r] = ok ? Q : (v2f){0.f, 0.f};
        }
    }

    // chunk-0 state is identically zero -> registers; buffer parity
    // guarantees write-before-read for every later chunk.
    v2f yc[RPL], yp[RPL];
#pragma unroll
    for (int r = 0; r < RPL; r++) { yc[r] = (v2f){0.f, 0.f}; yp[r] = (v2f){0.f, 0.f}; }

    // source (40,96): window col 96-J0 - always even
    int sr = 40 - I0, sc = 96 - J0;
    bool wave_src = (sr >= RPL * w) && (sr < RPL * w + RPL);
    int src_rl = sr - RPL * w;
    float srcm = (2 * l == sc) ? 1.f : 0.f;

    // probes (160,{48,96,144}): row 160 -> bi==26, window row 21 (wave 4, r=1)
    int pcl = 2 * l + J0;             // this lane's global .x column
    bool wave_prb = (bi == 26) && (w == 4);
    const int prb_rl = 1;
    bool is_prb = (cj == 0) ? (pcl == 48) : (pcl == 96 || pcl == 144);
    float prbm = is_prb ? 1.f : 0.f;
    float pacc = 0.f;                 // accumulates across ALL chunks

    v2f uph, dnh;
    __syncthreads();                  // hb zero-init + xs visible

// row update: yn = c + Q*(p-c) + K*(S-4c) — packed fp32, 2 DPP per 2 cells
#define ROWC(CUR, PRV, rr_, UP, DN, XSV, YN) do {                              \
    v2f cv = CUR[rr_];                                                         \
    float lf0 = dpp_up1(cv.y);                                                 \
    float rt1 = dpp_dn1(cv.x);                                                 \
    v2f h = (v2f){lf0, rt1} + __builtin_shufflevector(cv, cv, 1, 0);           \
    v2f S = ((UP) + (DN)) + h;                                                 \
    YN = cv + Qa[rr_] * (PRV[rr_] - cv) + Ka[rr_] * (S - 4.0f * cv);           \
    if (wave_src && (rr_) == src_rl) YN.x += srcm * (XSV);                     \
    if (wave_prb && (rr_) == prb_rl) { float q = prbm * YN.x; pacc += q * YN.x; } \
} while (0)

#define STEP(CUR, PRV, PH, SIDX) do {                                          \
    v2f t0, t4;                                                                \
    ROWC(CUR, PRV, 0, uph,    CUR[1], xv[SIDX], t0);                           \
    ROWC(CUR, PRV, 4, CUR[3], dnh,    xv[SIDX], t4);                           \
    hb[PH][0][w + 1][l] = t0;                                                  \
    hb[PH][1][w + 1][l] = t4;                                                  \
    PRV[0] = t0; PRV[4] = t4;                                                  \
    _Pragma("unroll")                                                          \
    for (int r = 1; r <= 3; r++) {                                             \
        v2f y;                                                                 \
        ROWC(CUR, PRV, r, CUR[r - 1], CUR[r + 1], xv[SIDX], y);                \
        PRV[r] = y;                                                            \
    }                                                                          \
    __syncthreads();                                                           \
    uph = hb[PH][1][w][l];                                                     \
    dnh = hb[PH][0][w + 2][l];                                                 \
} while (0)

#pragma unroll 1
    for (int chunk = 0; chunk < NCHUNK; chunk++) {
        // source amplitudes for this chunk (LDS broadcast -> registers)
        float xv[TCH];
#pragma unroll
        for (int i = 0; i < TCH; i++) xv[i] = xs[chunk * TCH + i];

        if (chunk) {
            // wait for the <=14 producer blocks to finish chunk-1
            // (counting flags: each chunk completion adds 2)
            if (dvalid) {
                while (__hip_atomic_load(&flags[dfi], __ATOMIC_RELAXED,
                                         __HIP_MEMORY_SCOPE_AGENT) < 2 * chunk) {}
            }
            __syncthreads();

            // reload the 40x128 state window. All producer stores were sc0 sc1
            // (visible at the coherent point = Infinity Cache), so plain
            // coherent loads suffice — NO cache-maintenance fence needed.
            int pin = chunk & 1;
            const float* curg = ws + ((pin * 2 + 0) * NBATCH + b) * CELLS;
            const float* prvg = ws + ((pin * 2 + 1) * NBATCH + b) * CELLS;
            int  idxr[RPL];
            bool okr[RPL];
#pragma unroll
            for (int r = 0; r < RPL; r++) {
                int gi = row0 + r;
                okr[r]  = cok && gi >= 0 && gi < NXY;
                idxr[r] = okr[r] ? gi * NXY + gj : 0;   // safe dummy addr
            }
            v2f c0, c1, c2, c3, c4, p0, p1, p2, p3, p4;
            asm volatile(
                "global_load_dwordx2 %0, %10, off sc0 sc1\n\t"
                "global_load_dwordx2 %1, %11, off sc0 sc1\n\t"
                "global_load_dwordx2 %2, %12, off sc0 sc1\n\t"
                "global_load_dwordx2 %3, %13, off sc0 sc1\n\t"
                "global_load_dwordx2 %4, %14, off sc0 sc1\n\t"
                "global_load_dwordx2 %5, %15, off sc0 sc1\n\t"
                "global_load_dwordx2 %6, %16, off sc0 sc1\n\t"
                "global_load_dwordx2 %7, %17, off sc0 sc1\n\t"
                "global_load_dwordx2 %8, %18, off sc0 sc1\n\t"
                "global_load_dwordx2 %9, %19, off sc0 sc1\n\t"
                "s_waitcnt vmcnt(0)"
                : "=&v"(c0), "=&v"(c1), "=&v"(c2), "=&v"(c3), "=&v"(c4),
                  "=&v"(p0), "=&v"(p1), "=&v"(p2), "=&v"(p3), "=&v"(p4)
                : "v"(curg + idxr[0]), "v"(curg + idxr[1]), "v"(curg + idxr[2]),
                  "v"(curg + idxr[3]), "v"(curg + idxr[4]),
                  "v"(prvg + idxr[0]), "v"(prvg + idxr[1]), "v"(prvg + idxr[2]),
                  "v"(prvg + idxr[3]), "v"(prvg + idxr[4])
                : "memory");
            yc[0] = okr[0] ? c0 : (v2f){0.f, 0.f};
            yc[1] = okr[1] ? c1 : (v2f){0.f, 0.f};
            yc[2] = okr[2] ? c2 : (v2f){0.f, 0.f};
            yc[3] = okr[3] ? c3 : (v2f){0.f, 0.f};
            yc[4] = okr[4] ? c4 : (v2f){0.f, 0.f};
            yp[0] = okr[0] ? p0 : (v2f){0.f, 0.f};
            yp[1] = okr[1] ? p1 : (v2f){0.f, 0.f};
            yp[2] = okr[2] ? p2 : (v2f){0.f, 0.f};
            yp[3] = okr[3] ? p3 : (v2f){0.f, 0.f};
            yp[4] = okr[4] ? p4 : (v2f){0.f, 0.f};
        }

        // prologue halo exchange (parity 0)
        hb[0][0][w + 1][l] = yc[0];
        hb[0][1][w + 1][l] = yc[4];
        __syncthreads();
        uph = hb[0][1][w][l];
        dnh = hb[0][0][w + 2][l];

#pragma unroll
        for (int s2 = 0; s2 < TCH / 2; s2++) {
            STEP(yc, yp, 1, 2 * s2);        // new cur -> yp, writes hb[1]
            STEP(yp, yc, 0, 2 * s2 + 1);    // new cur -> yc, writes hb[0]
        }
        // yc = y(t_end), yp = y(t_end-1); clean on window rows [16,24), cols [16,112)

        // EARLY SIGNAL: only waves 3 and 4 own out rows (window rows 17..22),
        // so they store, drain their own vmcnt, and each bump the counting
        // flag — no block-wide barrier or blanket vmcnt on the release path.
        // Consumers wait for flag >= 2*chunk (both waves done => both drained).
        if (chunk != NCHUNK - 1) {
            if (w == 3 || w == 4) {           // wave-uniform branch
                int pout = (chunk & 1) ^ 1;
                float* ncurg = ws + ((pout * 2 + 0) * NBATCH + b) * CELLS;
                float* nprvg = ws + ((pout * 2 + 1) * NBATCH + b) * CELLS;
#pragma unroll
                for (int r = 0; r < RPL; r++) {
                    int gi = row0 + r;
                    if (gi >= OUTR * bi && gi < OUTR * bi + OUTR && l >= 8 && l < 56) {
                        int idx = gi * NXY + gj;
                        asm volatile(
                            "global_store_dwordx2 %0, %2, off sc0 sc1\n\t"
                            "global_store_dwordx2 %1, %3, off sc0 sc1"
                            :: "v"(ncurg + idx), "v"(nprvg + idx),
                               "v"(yc[r]), "v"(yp[r])
                            : "memory");
                    }
                }
                asm volatile("s_waitcnt vmcnt(0)" ::: "memory");
                if (l == 0)
                    __hip_atomic_fetch_add(&flags[blk], 1, __ATOMIC_RELAXED,
                                           __HIP_MEMORY_SCOPE_AGENT);
            }
        } else {
            // last chunk: publish probe energy (unique writer per (b,pid)),
            // then the same wave-3/4 signal so block 0 can finalize.
            if (wave_prb && is_prb) {
                float* ip = ws + I_OFF + b * 3 + (pcl / 48 - 1);
                asm volatile("global_store_dword %0, %1, off sc0 sc1"
                             :: "v"(ip), "v"(pacc) : "memory");
            }
            if (w == 3 || w == 4) {
                asm volatile("s_waitcnt vmcnt(0)" ::: "memory");
                if (l == 0)
                    __hip_atomic_fetch_add(&flags[blk], 1, __ATOMIC_RELAXED,
                                           __HIP_MEMORY_SCOPE_AGENT);
            }
        }
    }
#undef STEP
#undef ROWC

    // finalization: block 0 waits for the 8 probe-owning blocks
    // (blk = b*64 + 26*2 + cj) to fully complete, then normalizes.
    if (blk == 0) {
        if (t < 8) {
            int pb = (t >> 1) * 64 + 52 + (t & 1);
            while (__hip_atomic_load(&flags[pb], __ATOMIC_RELAXED,
                                     __HIP_MEMORY_SCOPE_AGENT) < 2 * NCHUNK) {}
        }
        __syncthreads();
        if (t < 12) {
            const float* I = ws + I_OFF;
            int bb = t / 3;
            float s = 0.f;
#pragma unroll
            for (int k = 0; k < 3; k++)
                s += __hip_atomic_load(I + 3 * bb + k, __ATOMIC_RELAXED,
                                       __HIP_MEMORY_SCOPE_AGENT);
            float num = __hip_atomic_load(I + t, __ATOMIC_RELAXED,
                                          __HIP_MEMORY_SCOPE_AGENT);
            out[t] = num / s;
        }
    }
}

extern "C" void kernel_launch(void* const* d_in, const int* in_sizes, int n_in,
                              void* d_out, int out_size, void* d_ws, size_t ws_size,
                              hipStream_t stream) {
    const float* x   = (const float*)d_in[0];   // (4,256) fp32
    const float* rho = (const float*)d_in[1];   // (192,192) fp32
    float* ws  = (float*)d_ws;
    float* outp = (float*)d_out;

    // zero the probe area + flags (poisoned between iterations)
    hipMemsetAsync((char*)d_ws + I_OFF * sizeof(float), 0,
                   (64 + NBLKS) * sizeof(float), stream);

    // plain launch: co-residency guaranteed by capacity (see kernel comment)
    wave_k<<<dim3(NBLKS), dim3(TPB), 0, stream>>>(x, rho, ws, outp);
}

// Round 5
// 194.410 us; speedup vs baseline: 3.1271x; 1.0674x over previous
//
#include <hip/hip_runtime.h>
#include <math.h>

#define NXY    192
#define CELLS  (NXY*NXY)
#define NBATCH 4
#define NSTEPS 256
#define TCH    16                 // steps per chunk (= halo radius)
#define NCHUNK (NSTEPS/TCH)       // 16
#define TPB    512                // 8 waves -> 2 waves/SIMD
#define NW     8
#define RPL    5                  // rows per wave (40-row window / 8 waves)
#define OUTR   6                  // out rows per tile
#define NBLKS  256                // 32 row-tiles x 2 col-tiles x 4 batches
// in-tile 128 cols x 40 rows; out-tile 96 cols x 6 rows (window rows [17,23))

// workspace layout (float offsets): 16 state arrays + probe area + flags
#define I_OFF   (16*CELLS)
#define FLG_OFF (I_OFF + 64)      // int flags[NBLKS], monotonic chunk counters

typedef float v2f __attribute__((ext_vector_type(2)));

__device__ __forceinline__ float dpp_up1(float v) {   // lane i <- lane i-1
    int r = __builtin_amdgcn_update_dpp(0, __builtin_bit_cast(int, v),
                                        0x138, 0xf, 0xf, true); // wave_shr:1
    return __builtin_bit_cast(float, r);
}
__device__ __forceinline__ float dpp_dn1(float v) {   // lane i <- lane i+1
    int r = __builtin_amdgcn_update_dpp(0, __builtin_bit_cast(int, v),
                                        0x130, 0xf, 0xf, true); // wave_shl:1
    return __builtin_bit_cast(float, r);
}

__device__ __forceinline__ float pml_prof(int i) {
    int t;
    if (i <= 20)            t = 20 - i;
    else if (i >= NXY - 21) t = i - (NXY - 21);
    else                    return 0.0f;
    float u  = (float)t * 0.05f;
    float u2 = u * u;
    return 3.0f * u2 * u2;
}

// Plain (non-cooperative) launch: co-residency is guaranteed by capacity —
// VGPR 56 -> 32 waves/CU, LDS 21.5KB -> 4 blocks/CU, so capacity >= 1024
// blocks for a 256-block grid; every block is resident before any spin.
__global__ __launch_bounds__(TPB, 1)
void wave_k(const float* __restrict__ x, const float* __restrict__ rho,
            float* __restrict__ ws, float* __restrict__ out) {
    // XCD-contiguous remap (bijective, 256 = 8 XCD x 32)
    int blk = ((blockIdx.x & 7) << 5) | (blockIdx.x >> 3);
    int b  = blk / 64;                // batch
    int r_ = blk % 64;
    int bi = r_ >> 1, cj = r_ & 1;    // 32 row-tiles x 2 col-tiles
    int I0 = OUTR * bi - 17;          // window row origin (40 rows)
    int J0 = 96 * cj - 16;            // window col origin (128 cols)
    int t  = threadIdx.x;
    int w  = t >> 6;                  // wave 0..7, owns window rows [5w,5w+5)
    int l  = t & 63;                  // lane: local cols 2l, 2l+1
    int row0 = I0 + RPL * w;
    int gj   = J0 + 2 * l;

    int* flags = (int*)(ws + FLG_OFF);
    // dependency set: row-tiles bi-3..bi+3 (clamped), both col-tiles, same b.
    // Symmetric relation -> also protects WAR on the parity buffers.
    // Self-flag excluded (self-sync is trivial; polling it adds an L3
    // store->load round trip to every chunk boundary). Only wave 0 polls.
    int drt = bi + (t >> 1) - 3;
    int dfi = b * 64 + drt * 2 + (t & 1);
    bool dvalid = (t < 14) && (drt >= 0) && (drt < 32) &&
                  !(drt == bi && (t & 1) == cj);

    // [parity][top/bot][slot 0..9][lane]; wave w writes slot w+1;
    // reads up from slot w, down from slot w+2; slots 0,9 stay zero.
    __shared__ v2f hb[2][2][NW + 2][64];
    __shared__ float xs[NSTEPS];
    for (int k = t; k < 2 * 2 * (NW + 2) * 64; k += TPB)
        ((v2f*)hb)[k] = (v2f){0.f, 0.f};
    if (t < NSTEPS) xs[t] = x[b * NSTEPS + t];   // this batch's source trace

    bool cok = (gj >= 0 && gj < NXY);

    // ---- K (=a1*c2/H2) and Q (=1-2*a1) computed once, in-register ----
    // (verified: lane-edge DPP zeros only touch window cols 0/127,
    // outside the clean region)
    v2f Ka[RPL], Qa[RPL];
    {
        v2f rv[RPL + 2];
#pragma unroll
        for (int r = 0; r < RPL + 2; r++) {
            int gi = row0 - 1 + r;
            bool ok = cok && gi >= 0 && gi < NXY;
            rv[r] = ok ? *(const v2f*)(rho + gi * NXY + gj) : (v2f){0.f, 0.f};
        }
        const float IH2 = (float)(1.0 / (2.01 * 2.01));
#pragma unroll
        for (int r = 0; r < RPL; r++) {
            int gi = row0 + r;
            v2f rc = rv[r + 1], ru = rv[r], rd = rv[r + 2];
            float lf = dpp_up1(rc.y);
            float rt = dpp_dn1(rc.x);
            float bx = pml_prof(gi);
            v2f K, Q;
            {
                float lpf = 0.5f * rc.x + 0.125f * ((ru.x + rd.x) + (lf + rc.y));
                float p   = 0.5f * (1.0f + tanhf(100.0f * (lpf - 0.5f)));
                float c   = 1.0f - 0.1f * p;
                float by  = pml_prof(gj);
                float bb  = sqrtf(bx * bx + by * by);
                float a1  = 1.0f / (1.0f + 0.5f * bb);
                K.x = a1 * (c * c * IH2);
                Q.x = 1.0f - 2.0f * a1;
            }
            {
                float lpf = 0.5f * rc.y + 0.125f * ((ru.y + rd.y) + (rc.x + rt));
                float p   = 0.5f * (1.0f + tanhf(100.0f * (lpf - 0.5f)));
                float c   = 1.0f - 0.1f * p;
                float by  = pml_prof(gj + 1);
                float bb  = sqrtf(bx * bx + by * by);
                float a1  = 1.0f / (1.0f + 0.5f * bb);
                K.y = a1 * (c * c * IH2);
                Q.y = 1.0f - 2.0f * a1;
            }
            bool ok = cok && gi >= 0 && gi < NXY;
            Ka[r] = ok ? K : (v2f){0.f, 0.f};   // out-of-domain: K=Q=0 -> 0 forever
            Qa[r] = ok ? Q : (v2f){0.f, 0.f};
        }
    }

    // chunk-0 state is identically zero -> registers; buffer parity
    // guarantees write-before-read for every later chunk.
    v2f yc[RPL], yp[RPL];
#pragma unroll
    for (int r = 0; r < RPL; r++) { yc[r] = (v2f){0.f, 0.f}; yp[r] = (v2f){0.f, 0.f}; }

    // source (40,96): window col 96-J0 - always even
    int sr = 40 - I0, sc = 96 - J0;
    bool wave_src = (sr >= RPL * w) && (sr < RPL * w + RPL);
    int src_rl = sr - RPL * w;
    float srcm = (2 * l == sc) ? 1.f : 0.f;

    // probes (160,{48,96,144}): row 160 -> bi==26, window row 21 (wave 4, r=1)
    int pcl = 2 * l + J0;             // this lane's global .x column
    bool wave_prb = (bi == 26) && (w == 4);
    const int prb_rl = 1;
    bool is_prb = (cj == 0) ? (pcl == 48) : (pcl == 96 || pcl == 144);
    float prbm = is_prb ? 1.f : 0.f;
    float pacc = 0.f;                 // accumulates across ALL chunks

    v2f uph, dnh;
    __syncthreads();                  // hb zero-init + xs visible

// row update: yn = c + Q*(p-c) + K*(S-4c) — packed fp32, 2 DPP per 2 cells
#define ROWC(CUR, PRV, rr_, UP, DN, XSV, YN) do {                              \
    v2f cv = CUR[rr_];                                                         \
    float lf0 = dpp_up1(cv.y);                                                 \
    float rt1 = dpp_dn1(cv.x);                                                 \
    v2f h = (v2f){lf0, rt1} + __builtin_shufflevector(cv, cv, 1, 0);           \
    v2f S = ((UP) + (DN)) + h;                                                 \
    YN = cv + Qa[rr_] * (PRV[rr_] - cv) + Ka[rr_] * (S - 4.0f * cv);           \
    if (wave_src && (rr_) == src_rl) YN.x += srcm * (XSV);                     \
    if (wave_prb && (rr_) == prb_rl) { float q = prbm * YN.x; pacc += q * YN.x; } \
} while (0)

// LDS-latency-hiding order: interior rows 1..3 first (independent of the
// halo regs uph/dnh read right after the previous barrier), boundary rows
// 0/4 last. CUR[] is read-only within a step; rows 0/4 only read
// PRV[0]/PRV[4], so the early PRV[1..3] writes are safe.
#define STEP(CUR, PRV, PH, SIDX) do {                                          \
    v2f y1, y2, y3, t0, t4;                                                    \
    ROWC(CUR, PRV, 1, CUR[0], CUR[2], xv[SIDX], y1);                           \
    ROWC(CUR, PRV, 2, CUR[1], CUR[3], xv[SIDX], y2);                           \
    ROWC(CUR, PRV, 3, CUR[2], CUR[4], xv[SIDX], y3);                           \
    ROWC(CUR, PRV, 0, uph,    CUR[1], xv[SIDX], t0);                           \
    ROWC(CUR, PRV, 4, CUR[3], dnh,    xv[SIDX], t4);                           \
    hb[PH][0][w + 1][l] = t0;                                                  \
    hb[PH][1][w + 1][l] = t4;                                                  \
    PRV[0] = t0; PRV[1] = y1; PRV[2] = y2; PRV[3] = y3; PRV[4] = t4;           \
    __syncthreads();                                                           \
    uph = hb[PH][1][w][l];                                                     \
    dnh = hb[PH][0][w + 2][l];                                                 \
} while (0)

#pragma unroll 1
    for (int chunk = 0; chunk < NCHUNK; chunk++) {
        // source amplitudes for this chunk (LDS broadcast -> registers)
        float xv[TCH];
#pragma unroll
        for (int i = 0; i < TCH; i++) xv[i] = xs[chunk * TCH + i];

        if (chunk) {
            // wait for the <=13 producer blocks to finish chunk-1
            // (agent-scope poll: sc1 load, bypasses non-coherent L2)
            if (dvalid) {
                while (__hip_atomic_load(&flags[dfi], __ATOMIC_RELAXED,
                                         __HIP_MEMORY_SCOPE_AGENT) < chunk) {}
            }
            __syncthreads();

            // reload the 40x128 state window. All producer stores were sc0 sc1
            // (visible at the coherent point = Infinity Cache), so plain
            // coherent loads suffice — NO cache-maintenance fence needed.
            int pin = chunk & 1;
            const float* curg = ws + ((pin * 2 + 0) * NBATCH + b) * CELLS;
            const float* prvg = ws + ((pin * 2 + 1) * NBATCH + b) * CELLS;
            int  idxr[RPL];
            bool okr[RPL];
#pragma unroll
            for (int r = 0; r < RPL; r++) {
                int gi = row0 + r;
                okr[r]  = cok && gi >= 0 && gi < NXY;
                idxr[r] = okr[r] ? gi * NXY + gj : 0;   // safe dummy addr
            }
            v2f c0, c1, c2, c3, c4, p0, p1, p2, p3, p4;
            asm volatile(
                "global_load_dwordx2 %0, %10, off sc0 sc1\n\t"
                "global_load_dwordx2 %1, %11, off sc0 sc1\n\t"
                "global_load_dwordx2 %2, %12, off sc0 sc1\n\t"
                "global_load_dwordx2 %3, %13, off sc0 sc1\n\t"
                "global_load_dwordx2 %4, %14, off sc0 sc1\n\t"
                "global_load_dwordx2 %5, %15, off sc0 sc1\n\t"
                "global_load_dwordx2 %6, %16, off sc0 sc1\n\t"
                "global_load_dwordx2 %7, %17, off sc0 sc1\n\t"
                "global_load_dwordx2 %8, %18, off sc0 sc1\n\t"
                "global_load_dwordx2 %9, %19, off sc0 sc1\n\t"
                "s_waitcnt vmcnt(0)"
                : "=&v"(c0), "=&v"(c1), "=&v"(c2), "=&v"(c3), "=&v"(c4),
                  "=&v"(p0), "=&v"(p1), "=&v"(p2), "=&v"(p3), "=&v"(p4)
                : "v"(curg + idxr[0]), "v"(curg + idxr[1]), "v"(curg + idxr[2]),
                  "v"(curg + idxr[3]), "v"(curg + idxr[4]),
                  "v"(prvg + idxr[0]), "v"(prvg + idxr[1]), "v"(prvg + idxr[2]),
                  "v"(prvg + idxr[3]), "v"(prvg + idxr[4])
                : "memory");
            yc[0] = okr[0] ? c0 : (v2f){0.f, 0.f};
            yc[1] = okr[1] ? c1 : (v2f){0.f, 0.f};
            yc[2] = okr[2] ? c2 : (v2f){0.f, 0.f};
            yc[3] = okr[3] ? c3 : (v2f){0.f, 0.f};
            yc[4] = okr[4] ? c4 : (v2f){0.f, 0.f};
            yp[0] = okr[0] ? p0 : (v2f){0.f, 0.f};
            yp[1] = okr[1] ? p1 : (v2f){0.f, 0.f};
            yp[2] = okr[2] ? p2 : (v2f){0.f, 0.f};
            yp[3] = okr[3] ? p3 : (v2f){0.f, 0.f};
            yp[4] = okr[4] ? p4 : (v2f){0.f, 0.f};
        }

        // prologue halo exchange (parity 0)
        hb[0][0][w + 1][l] = yc[0];
        hb[0][1][w + 1][l] = yc[4];
        __syncthreads();
        uph = hb[0][1][w][l];
        dnh = hb[0][0][w + 2][l];

#pragma unroll
        for (int s2 = 0; s2 < TCH / 2; s2++) {
            STEP(yc, yp, 1, 2 * s2);        // new cur -> yp, writes hb[1]
            STEP(yp, yc, 0, 2 * s2 + 1);    // new cur -> yc, writes hb[0]
        }
        // yc = y(t_end), yp = y(t_end-1); clean on window rows [16,24), cols [16,112)

        if (chunk != NCHUNK - 1) {
            // store out-tile coherently (sc0 sc1 -> Infinity Cache):
            // rows [6bi,6bi+6) (window rows [17,23)), lanes 8..55
            int pout = (chunk & 1) ^ 1;
            float* ncurg = ws + ((pout * 2 + 0) * NBATCH + b) * CELLS;
            float* nprvg = ws + ((pout * 2 + 1) * NBATCH + b) * CELLS;
#pragma unroll
            for (int r = 0; r < RPL; r++) {
                int gi = row0 + r;
                if (gi >= OUTR * bi && gi < OUTR * bi + OUTR && l >= 8 && l < 56) {
                    int idx = gi * NXY + gj;
                    asm volatile(
                        "global_store_dwordx2 %0, %2, off sc0 sc1\n\t"
                        "global_store_dwordx2 %1, %3, off sc0 sc1"
                        :: "v"(ncurg + idx), "v"(nprvg + idx),
                           "v"(yc[r]), "v"(yp[r])
                        : "memory");
                }
            }
        } else {
            // last chunk: publish probe energy (unique writer per (b,pid))
            if (wave_prb && is_prb) {
                float* ip = ws + I_OFF + b * 3 + (pcl / 48 - 1);
                asm volatile("global_store_dword %0, %1, off sc0 sc1"
                             :: "v"(ip), "v"(pacc) : "memory");
            }
        }

        // release: drain this wave's coherent stores (compiler can't see the
        // asm stores' vmcnt), barrier (all waves drained), then publish flag
        // at agent scope. No wbl2 needed — data already at coherent point.
        asm volatile("s_waitcnt vmcnt(0)" ::: "memory");
        __syncthreads();
        if (t == 0) {
            __hip_atomic_store(&flags[blk], chunk + 1, __ATOMIC_RELAXED,
                               __HIP_MEMORY_SCOPE_AGENT);
        }
    }
#undef STEP
#undef ROWC

    // finalization: block 0 waits for the 8 probe-owning blocks
    // (blk = b*64 + 26*2 + cj), then normalizes. I[] reads agent-coherent.
    if (blk == 0) {
        if (t < 8) {
            int pb = (t >> 1) * 64 + 52 + (t & 1);
            while (__hip_atomic_load(&flags[pb], __ATOMIC_RELAXED,
                                     __HIP_MEMORY_SCOPE_AGENT) < NCHUNK) {}
        }
        __syncthreads();
        if (t < 12) {
            const float* I = ws + I_OFF;
            int bb = t / 3;
            float s = 0.f;
#pragma unroll
            for (int k = 0; k < 3; k++)
                s += __hip_atomic_load(I + 3 * bb + k, __ATOMIC_RELAXED,
                                       __HIP_MEMORY_SCOPE_AGENT);
            float num = __hip_atomic_load(I + t, __ATOMIC_RELAXED,
                                          __HIP_MEMORY_SCOPE_AGENT);
            out[t] = num / s;
        }
    }
}

extern "C" void kernel_launch(void* const* d_in, const int* in_sizes, int n_in,
                              void* d_out, int out_size, void* d_ws, size_t ws_size,
                              hipStream_t stream) {
    const float* x   = (const float*)d_in[0];   // (4,256) fp32
    const float* rho = (const float*)d_in[1];   // (192,192) fp32
    float* ws  = (float*)d_ws;
    float* outp = (float*)d_out;

    // zero the probe area + flags (poisoned between iterations)
    hipMemsetAsync((char*)d_ws + I_OFF * sizeof(float), 0,
                   (64 + NBLKS) * sizeof(float), stream);

    // plain launch: co-residency guaranteed by capacity (see kernel comment)
    wave_k<<<dim3(NBLKS), dim3(TPB), 0, stream>>>(x, rho, ws, outp);
}